// Round 4
// baseline (3026.835 us; speedup 1.0000x reference)
//
#include <hip/hip_runtime.h>
#include <cstdio>
#include <cstdint>

#define BB 16
#define HH 48
#define WW 48
#define DD 384
#define NTOK 2304            // HH*WW
#define EPS 1e-5f
#define SZB 28311552u        // BB*NTOK*DD*2 bytes (one bf16 tensor); xlo = xhi + SZB

typedef __attribute__((ext_vector_type(4))) float f32x4;
typedef __attribute__((ext_vector_type(8))) short bf16x8;
typedef __attribute__((ext_vector_type(4))) short bf16x4;

__device__ __forceinline__ unsigned short f2bf(float f) {
  uint32_t u = __float_as_uint(f);
  uint32_t r = (u + 0x7FFFu + ((u >> 16) & 1u)) >> 16;
  return (unsigned short)r;
}
__device__ __forceinline__ float bf2f(short s) {
  return __uint_as_float(((uint32_t)(unsigned short)s) << 16);
}

// ---------------- K1: x + posenc -> hi/lo bf16 ----------------
__global__ void k_prep(const float* __restrict__ x, const float* __restrict__ Wp,
                       const float* __restrict__ bp, short* __restrict__ xhi,
                       short* __restrict__ xlo) {
  size_t e = ((size_t)blockIdx.x * 256 + threadIdx.x) * 4;
  int d = (int)(e % DD);
  int n = (int)((e / DD) % NTOK);
  float fh = (float)(n / WW), fw = (float)(n % WW);
  f32x4 v = *(const f32x4*)(x + e);
  bf16x4 hv, lv;
#pragma unroll
  for (int j = 0; j < 4; ++j) {
    float pe = fh * Wp[d + j] + fw * Wp[DD + d + j] + bp[d + j];
    float val = v[j] + pe;
    unsigned short hb = f2bf(val);
    hv[j] = (short)hb;
    lv[j] = (short)f2bf(val - bf2f((short)hb));
  }
  *(bf16x4*)(xhi + e) = hv;
  *(bf16x4*)(xlo + e) = lv;
}

// ---------------- KV: build fragment-ordered V tensor ----------------
// vfrag[b][mt=0..143][db=0..23][lane=0..63][j=0..3] = xhi[b][mt*16 + (lane>>4)*4 + j][db*16 + (lane&15)]
__global__ void k_vfrag(const short* __restrict__ xhi, short* __restrict__ vfrag) {
  __shared__ __attribute__((aligned(16))) short tile[16 * 384];
  const int b = blockIdx.y, mt = blockIdx.x, tid = threadIdx.x;
  const char* src = (const char*)(xhi + ((size_t)b * NTOK + mt * 16) * DD);
#pragma unroll
  for (int c = 0; c < 3; ++c) {
    int g = c * 4096 + tid * 16;
    *(uint4*)((char*)tile + g) = *(const uint4*)(src + g);   // 16 rows contiguous
  }
  __syncthreads();
  char* dst = (char*)vfrag + ((size_t)b * 144 + mt) * 12288;
#pragma unroll
  for (int c = 0; c < 6; ++c) {
    int u = c * 256 + tid;
    int db = u >> 6, l = u & 63;
    bf16x4 vv;
#pragma unroll
    for (int j = 0; j < 4; ++j)
      vv[j] = tile[((l >> 4) * 4 + j) * 384 + db * 16 + (l & 15)];
    *(bf16x4*)(dst + u * 8) = vv;
  }
}

// ---------------- KW: W1^T, W2^T bf16 ----------------
__global__ void k_wprep(const float* __restrict__ W1, const float* __restrict__ W2,
                        short* __restrict__ w1t, short* __restrict__ w2t) {
  int idx = blockIdx.x * 256 + threadIdx.x;
  int r = idx / DD, c = idx % DD;
  w1t[c * DD + r] = (short)f2bf(W1[idx]);
  w2t[c * DD + r] = (short)f2bf(W2[idx]);
}

// ---------------- K2: flash attention (KVB=16, lane-local P, global V-frags) ----
#define NIT 144              // NTOK / 16

__global__ __launch_bounds__(256, 3)
void k_attn(const short* __restrict__ xhi, const short* __restrict__ xlo,
            const short* __restrict__ vfrag, short* __restrict__ aout) {
  // K tile per 16 tokens: hi [0,12288) + lo [12288,24576), row stride 768B,
  // byte-swizzle col ^= (row&7)<<4. Double-buffered. Nothing else in LDS.
  __shared__ __attribute__((aligned(16))) char skv[2][24576];
  const int tid = threadIdx.x;
  const int lane = tid & 63, wave = tid >> 6;
  const int ln15 = lane & 15, lg = lane >> 4;
  // XCD-aware swizzle: 2 batches per XCD (72 blocks/XCD).
  const int lid = blockIdx.x;
  const int xcd = lid & 7, slot = lid >> 3;
  const int b = 2 * xcd + (slot >= 36 ? 1 : 0);
  const int qt = (slot >= 36) ? slot - 36 : slot;
  const int q0 = qt * 64;
  const int swz = (ln15 & 7) << 4;

  // staging offsets: 6 chunks of 16B per thread covering 24576 B
  uint32_t ldsoff[6], srcoff[6];
#pragma unroll
  for (int c = 0; c < 6; ++c) {
    int g = c * 4096 + tid * 16;
    int region = g >= 12288 ? 1 : 0;
    int rem = g - region * 12288;
    int row = rem / 768;
    int col = rem - row * 768;
    ldsoff[c] = (uint32_t)(region * 12288 + row * 768 + (col ^ ((row & 7) << 4)));
    srcoff[c] = (uint32_t)(row * 768 + col) + (region ? SZB : 0u);
  }
  const char* kbp = (const char*)xhi + (size_t)b * NTOK * 768;
  const char* vfb = (const char*)vfrag + (size_t)b * 1769472 + lane * 8;

  // Q hi fragments resident; Q lo streamed from global (L2-hot)
  bf16x8 qh[12];
  {
    const short* qp = xhi + ((size_t)b * NTOK + q0 + wave * 16 + ln15) * DD + lg * 8;
#pragma unroll
    for (int kf = 0; kf < 12; ++kf) qh[kf] = *(const bf16x8*)(qp + kf * 32);
  }
  const short* qlp = xlo + ((size_t)b * NTOK + q0 + wave * 16 + ln15) * DD + lg * 8;

  f32x4 o[24];
#pragma unroll
  for (int i = 0; i < 24; ++i) o[i] = f32x4{0.f, 0.f, 0.f, 0.f};
  float m1 = -INFINITY, l1 = 0.0f;

  // prologue: stage K(0) into buf 0
  {
#pragma unroll
    for (int c = 0; c < 6; ++c) {
      uint4 kst = *(const uint4*)(kbp + srcoff[c]);
      *(uint4*)(&skv[0][0] + ldsoff[c]) = kst;
    }
  }
  __syncthreads();
  int cur = 0;

#pragma unroll 1
  for (int t = 0; t < NIT; ++t) {
    const char* kc = &skv[cur][0];
    // ---- QK^T (split precision): 3 chains over 12 k-fragments ----
    f32x4 shh = f32x4{0.f, 0.f, 0.f, 0.f}, shl = shh, slh = shh;
    __builtin_amdgcn_s_setprio(1);
#pragma unroll
    for (int kf = 0; kf < 12; ++kf) {
      bf16x8 ql = *(const bf16x8*)(qlp + kf * 32);
      const int ca = (kf * 64 + lg * 16) ^ swz;
      bf16x8 ah = *(const bf16x8*)(kc + ln15 * 768 + ca);
      bf16x8 al = *(const bf16x8*)(kc + 12288 + ln15 * 768 + ca);
      shh = __builtin_amdgcn_mfma_f32_16x16x32_bf16(ah, qh[kf], shh, 0, 0, 0);
      shl = __builtin_amdgcn_mfma_f32_16x16x32_bf16(ah, ql, shl, 0, 0, 0);
      slh = __builtin_amdgcn_mfma_f32_16x16x32_bf16(al, qh[kf], slh, 0, 0, 0);
    }
    __builtin_amdgcn_s_setprio(0);
    f32x4 s;
#pragma unroll
    for (int r = 0; r < 4; ++r) s[r] = shh[r] + shl[r] + slh[r];

    // ---- softmax (lane owns q=ln15; m = lg*4 + r) ----
    float tmax = fmaxf(fmaxf(s[0], s[1]), fmaxf(s[2], s[3]));
    tmax = fmaxf(tmax, __shfl_xor(tmax, 16));
    tmax = fmaxf(tmax, __shfl_xor(tmax, 32));
    if (__any(tmax - m1 > 8.f)) {          // defer-max
      float mn = fmaxf(m1, tmax);
      float al_ = __expf(m1 - mn);
      float alr[4];
#pragma unroll
      for (int r = 0; r < 4; ++r) alr[r] = __shfl(al_, lg * 4 + r);
#pragma unroll
      for (int ob = 0; ob < 24; ++ob)
#pragma unroll
        for (int r = 0; r < 4; ++r) o[ob][r] *= alr[r];
      l1 *= al_;
      m1 = mn;
    }
    float rs = 0.0f;
    bf16x8 p8 = bf16x8{0, 0, 0, 0, 0, 0, 0, 0};
#pragma unroll
    for (int r = 0; r < 4; ++r) {
      float p = __expf(s[r] - m1);
      rs += p;
      p8[r] = (short)f2bf(p);
    }
    rs += __shfl_xor(rs, 16);
    rs += __shfl_xor(rs, 32);
    l1 += rs;

    // ---- issue K(t+1) global loads (drain hidden under PV) ----
    uint4 kst[6];
    if (t + 1 < NIT) {
      const char* kn = kbp + (size_t)(t + 1) * 12288;
#pragma unroll
      for (int c = 0; c < 6; ++c) kst[c] = *(const uint4*)(kn + srcoff[c]);
    }

    // ---- PV: O[q][d] += P[q][m] * V[m][d]; V-frags = coalesced 512B global loads ----
    const char* vf = vfb + (size_t)t * 12288;
    __builtin_amdgcn_s_setprio(1);
#pragma unroll
    for (int db = 0; db < 24; ++db) {
      bf16x4 vv = *(const bf16x4*)(vf + db * 512);
      bf16x8 v8 = bf16x8{vv[0], vv[1], vv[2], vv[3], 0, 0, 0, 0};
      o[db] = __builtin_amdgcn_mfma_f32_16x16x32_bf16(p8, v8, o[db], 0, 0, 0);
    }
    __builtin_amdgcn_s_setprio(0);

    // ---- write K(t+1) into other buffer, then barrier ----
    if (t + 1 < NIT) {
      char* kd = &skv[cur ^ 1][0];
#pragma unroll
      for (int c = 0; c < 6; ++c) *(uint4*)(kd + ldsoff[c]) = kst[c];
    }
    __syncthreads();
    cur ^= 1;
  }

  // epilogue: O /= l, store bf16
  float lr[4];
#pragma unroll
  for (int r = 0; r < 4; ++r) lr[r] = __shfl(l1, lg * 4 + r);
  short* ob_ = aout + ((size_t)b * NTOK + q0 + wave * 16) * DD;
#pragma unroll
  for (int db = 0; db < 24; ++db) {
#pragma unroll
    for (int r = 0; r < 4; ++r) {
      float v = o[db][r] / lr[r];
      ob_[(size_t)(lg * 4 + r) * DD + db * 16 + ln15] = (short)f2bf(v);
    }
  }
}

// ---------------- K3: MLP + residual + LN stats ----------------
__global__ __launch_bounds__(256, 2)
void k_mlp(const short* __restrict__ aout, const short* __restrict__ w1t,
           const short* __restrict__ w2t, const float* __restrict__ b1,
           const float* __restrict__ b2, const short* __restrict__ xhi,
           const short* __restrict__ xlo, float* __restrict__ out,
           float* __restrict__ stats) {
  __shared__ __attribute__((aligned(16))) short hid[4 * 16 * 392];
  __shared__ float redS[4], redQ[4];
  const int tid = threadIdx.x, lane = tid & 63, wave = tid >> 6;
  const int ln15 = lane & 15, lg = lane >> 4;
  const int row0 = blockIdx.x * 64;
  const int bb = row0 / NTOK;

  bf16x8 a[12];
  {
    const short* ap = aout + (size_t)(row0 + wave * 16 + ln15) * DD + lg * 8;
#pragma unroll
    for (int kf = 0; kf < 12; ++kf) a[kf] = *(const bf16x8*)(ap + kf * 32);
  }
  short* hw = &hid[wave * 16 * 392];
#pragma unroll 1
  for (int cb = 0; cb < 24; ++cb) {
    f32x4 acc = f32x4{0.f, 0.f, 0.f, 0.f};
#pragma unroll
    for (int kf = 0; kf < 12; ++kf) {
      bf16x8 wf = *(const bf16x8*)(w1t + (size_t)(cb * 16 + ln15) * DD + kf * 32 + lg * 8);
      acc = __builtin_amdgcn_mfma_f32_16x16x32_bf16(a[kf], wf, acc, 0, 0, 0);
    }
    float bias = b1[cb * 16 + ln15];
#pragma unroll
    for (int r = 0; r < 4; ++r) {
      float v = fmaxf(acc[r] + bias, 0.0f);
      hw[(lg * 4 + r) * 392 + cb * 16 + ln15] = (short)f2bf(v);
    }
  }
  __syncthreads();
  bf16x8 h[12];
#pragma unroll
  for (int kf = 0; kf < 12; ++kf)
    h[kf] = *(const bf16x8*)(&hw[ln15 * 392 + kf * 32 + lg * 8]);
  float ts = 0.f, tq = 0.f;
#pragma unroll 1
  for (int cb = 0; cb < 24; ++cb) {
    f32x4 acc = f32x4{0.f, 0.f, 0.f, 0.f};
#pragma unroll
    for (int kf = 0; kf < 12; ++kf) {
      bf16x8 wf = *(const bf16x8*)(w2t + (size_t)(cb * 16 + ln15) * DD + kf * 32 + lg * 8);
      acc = __builtin_amdgcn_mfma_f32_16x16x32_bf16(h[kf], wf, acc, 0, 0, 0);
    }
    int col = cb * 16 + ln15;
    float bias = b2[col];
#pragma unroll
    for (int r = 0; r < 4; ++r) {
      size_t row = (size_t)row0 + wave * 16 + lg * 4 + r;
      size_t idx = row * DD + col;
      float xv = bf2f(xhi[idx]) + bf2f(xlo[idx]);
      float y = acc[r] + bias + xv;
      out[idx] = y;
      ts += y;
      tq += y * y;
    }
  }
#pragma unroll
  for (int off = 32; off; off >>= 1) {
    ts += __shfl_xor(ts, off);
    tq += __shfl_xor(tq, off);
  }
  if (lane == 0) { redS[wave] = ts; redQ[wave] = tq; }
  __syncthreads();
  if (tid == 0) {
    atomicAdd(&stats[bb], redS[0] + redS[1] + redS[2] + redS[3]);
    atomicAdd(&stats[16 + bb], redQ[0] + redQ[1] + redQ[2] + redQ[3]);
  }
}

// ---------------- K4: LayerNorm ----------------
__global__ void k_ln(float* __restrict__ out, const float* __restrict__ stats) {
  size_t i4 = ((size_t)blockIdx.x * 256 + threadIdx.x) * 4;
  int b = (int)(i4 / ((size_t)NTOK * DD));
  const float cnt = (float)(NTOK * DD);
  float mean = stats[b] / cnt;
  float var = stats[16 + b] / cnt - mean * mean;
  float inv = rsqrtf(var + EPS);
  f32x4 v = *(f32x4*)(out + i4);
#pragma unroll
  for (int j = 0; j < 4; ++j) v[j] = (v[j] - mean) * inv;
  *(f32x4*)(out + i4) = v;
}

// ---------------- launcher ----------------
extern "C" void kernel_launch(void* const* d_in, const int* in_sizes, int n_in,
                              void* d_out, int out_size, void* d_ws, size_t ws_size,
                              hipStream_t stream) {
  const float* x  = (const float*)d_in[0];
  const float* Wp = (const float*)d_in[1];
  const float* bp = (const float*)d_in[2];
  const float* W1 = (const float*)d_in[3];
  const float* b1 = (const float*)d_in[4];
  const float* W2 = (const float*)d_in[5];
  const float* b2 = (const float*)d_in[6];
  float* out = (float*)d_out;

  const size_t SZ = (size_t)SZB;   // 28,311,552 bytes
  char* ws = (char*)d_ws;
  short* xhi   = (short*)ws;
  short* xlo   = (short*)(ws + SZ);      // MUST stay at xhi+SZB (staging offsets rely on it)
  short* vfrag = (short*)(ws + 2 * SZ);
  short* aout  = (short*)(ws + 3 * SZ);
  short* w1t   = (short*)(ws + 4 * SZ);
  short* w2t   = (short*)(ws + 4 * SZ + 294912);
  float* stats = (float*)(ws + 4 * SZ + 2 * 294912);
  const size_t need = 4 * SZ + 2 * 294912 + 128;
  if (ws_size < need) {
    fprintf(stderr, "kernel_launch: ws_size %zu < needed %zu\n", ws_size, need);
  }

  k_prep<<<13824, 256, 0, stream>>>(x, Wp, bp, xhi, xlo);
  k_vfrag<<<dim3(144, 16), 256, 0, stream>>>(xhi, vfrag);
  k_wprep<<<576, 256, 0, stream>>>(W1, W2, w1t, w2t);
  k_attn<<<576, 256, 0, stream>>>(xhi, xlo, vfrag, aout);
  hipMemsetAsync(stats, 0, 32 * sizeof(float), stream);
  k_mlp<<<576, 256, 0, stream>>>(aout, w1t, w2t, b1, b2, xhi, xlo, out, stats);
  k_ln<<<13824, 256, 0, stream>>>(out, stats);
}

// Round 5
// 1646.992 us; speedup vs baseline: 1.8378x; 1.8378x over previous
//
#include <hip/hip_runtime.h>
#include <cstdio>
#include <cstdint>

#define BB 16
#define HH 48
#define WW 48
#define DD 384
#define NTOK 2304            // HH*WW
#define EPS 1e-5f
#define SZB 28311552u        // BB*NTOK*DD*2 bytes (one bf16 tensor); xlo = xhi + SZB

typedef __attribute__((ext_vector_type(4))) float f32x4;
typedef __attribute__((ext_vector_type(8))) short bf16x8;
typedef __attribute__((ext_vector_type(4))) short bf16x4;

__device__ __forceinline__ unsigned short f2bf(float f) {
  uint32_t u = __float_as_uint(f);
  uint32_t r = (u + 0x7FFFu + ((u >> 16) & 1u)) >> 16;
  return (unsigned short)r;
}
__device__ __forceinline__ float bf2f(short s) {
  return __uint_as_float(((uint32_t)(unsigned short)s) << 16);
}

typedef __attribute__((address_space(3))) uint32_t lds_u32;
typedef __attribute__((address_space(1))) const uint32_t glob_u32;
__device__ __forceinline__ void gload_lds16(const void* g, void* l) {
  __builtin_amdgcn_global_load_lds((glob_u32*)g, (lds_u32*)l, 16, 0, 0);
}

// ---------------- K1: x + posenc -> hi/lo bf16 ----------------
__global__ void k_prep(const float* __restrict__ x, const float* __restrict__ Wp,
                       const float* __restrict__ bp, short* __restrict__ xhi,
                       short* __restrict__ xlo) {
  size_t e = ((size_t)blockIdx.x * 256 + threadIdx.x) * 4;
  int d = (int)(e % DD);
  int n = (int)((e / DD) % NTOK);
  float fh = (float)(n / WW), fw = (float)(n % WW);
  f32x4 v = *(const f32x4*)(x + e);
  bf16x4 hv, lv;
#pragma unroll
  for (int j = 0; j < 4; ++j) {
    float pe = fh * Wp[d + j] + fw * Wp[DD + d + j] + bp[d + j];
    float val = v[j] + pe;
    unsigned short hb = f2bf(val);
    hv[j] = (short)hb;
    lv[j] = (short)f2bf(val - bf2f((short)hb));
  }
  *(bf16x4*)(xhi + e) = hv;
  *(bf16x4*)(xlo + e) = lv;
}

// ---------------- KV: build fragment-ordered V tensor ----------------
// vfrag[b][mt][db][lane][j] = xhi[b][mt*16 + (lane>>4)*4 + j][db*16 + (lane&15)]
__global__ void k_vfrag(const short* __restrict__ xhi, short* __restrict__ vfrag) {
  __shared__ __attribute__((aligned(16))) short tile[16 * 384];
  const int b = blockIdx.y, mt = blockIdx.x, tid = threadIdx.x;
  const char* src = (const char*)(xhi + ((size_t)b * NTOK + mt * 16) * DD);
#pragma unroll
  for (int c = 0; c < 3; ++c) {
    int g = c * 4096 + tid * 16;
    *(uint4*)((char*)tile + g) = *(const uint4*)(src + g);
  }
  __syncthreads();
  char* dst = (char*)vfrag + ((size_t)b * 144 + mt) * 12288;
#pragma unroll
  for (int c = 0; c < 6; ++c) {
    int u = c * 256 + tid;
    int db = u >> 6, l = u & 63;
    bf16x4 vv;
#pragma unroll
    for (int j = 0; j < 4; ++j)
      vv[j] = tile[((l >> 4) * 4 + j) * 384 + db * 16 + (l & 15)];
    *(bf16x4*)(dst + u * 8) = vv;
  }
}

// ---------------- KW: W1^T, W2^T bf16 ----------------
__global__ void k_wprep(const float* __restrict__ W1, const float* __restrict__ W2,
                        short* __restrict__ w1t, short* __restrict__ w2t) {
  int idx = blockIdx.x * 256 + threadIdx.x;
  int r = idx / DD, c = idx % DD;
  w1t[c * DD + r] = (short)f2bf(W1[idx]);
  w2t[c * DD + r] = (short)f2bf(W2[idx]);
}

// ---------------- K2: flash attention ----------------
// q-tile 32 (2 waves), KVB=16, K hi+lo double-buffered in LDS via DMA,
// lane-local P (no P LDS), V from fragment-ordered global tensor (no V LDS).
#define NIT 144              // NTOK / 16

__global__ __launch_bounds__(128, 2)
void k_attn(const short* __restrict__ xhi, const short* __restrict__ xlo,
            const short* __restrict__ vfrag, short* __restrict__ aout) {
  // per buffer: hi [0,12288) + lo [12288,24576), row stride 768B,
  // read-swizzle col ^= (row&7)<<4, source pre-inverse-swizzled, dest linear.
  __shared__ __attribute__((aligned(16))) char skv[2][24576];
  const int tid = threadIdx.x;
  const int lane = tid & 63, wave = tid >> 6;      // wave 0..1
  const int ln15 = lane & 15, lg = lane >> 4;
  // XCD-aware swizzle: 2 batches per XCD (144 blocks/XCD).
  const int lid = blockIdx.x;
  const int xcd = lid & 7, slot = lid >> 3;        // slot 0..143
  const int b = 2 * xcd + (slot >= 72 ? 1 : 0);
  const int qt = (slot >= 72) ? slot - 72 : slot;
  const int q0 = qt * 32;
  const int swz = (ln15 & 7) << 4;

  // DMA source offsets: 12 chunks x 16B per thread cover 24576B; dest is linear.
  uint32_t srcoff[12];
#pragma unroll
  for (int c = 0; c < 12; ++c) {
    int g = c * 2048 + tid * 16;                   // dest byte
    int region = (g >= 12288) ? 1 : 0;             // 0=hi, 1=lo
    int rem = g - region * 12288;
    int row = rem / 768;
    int col = rem - row * 768;
    srcoff[c] = (uint32_t)(row * 768 + (col ^ ((row & 7) << 4))) + (region ? SZB : 0u);
  }
  const char* kbp = (const char*)xhi + (size_t)b * NTOK * 768;
  const char* vfb = (const char*)vfrag + (size_t)b * 1769472 + lane * 8;

  // Q hi fragments resident; Q lo streamed from global (L2-hot)
  bf16x8 qh[12];
  {
    const short* qp = xhi + ((size_t)b * NTOK + q0 + wave * 16 + ln15) * DD + lg * 8;
#pragma unroll
    for (int kf = 0; kf < 12; ++kf) qh[kf] = *(const bf16x8*)(qp + kf * 32);
  }
  const short* qlp = xlo + ((size_t)b * NTOK + q0 + wave * 16 + ln15) * DD + lg * 8;

  f32x4 o[24];
#pragma unroll
  for (int i = 0; i < 24; ++i) o[i] = f32x4{0.f, 0.f, 0.f, 0.f};
  float m1 = -INFINITY, l1 = 0.0f;
  bf16x8 p8 = bf16x8{0, 0, 0, 0, 0, 0, 0, 0};     // high half stays zero (k-slots 4..7)

  // prologue: stage K(0) into buf 0
#pragma unroll
  for (int c = 0; c < 12; ++c)
    gload_lds16(kbp + srcoff[c], &skv[0][0] + c * 2048 + tid * 16);
  __syncthreads();

#pragma unroll 1
  for (int t = 0; t < NIT; ++t) {
    // issue K(t+1) DMA into other buffer — drained at end-of-iter barrier
    if (t + 1 < NIT) {
      const char* kn = kbp + (size_t)(t + 1) * 12288;
      char* kd = &skv[(t + 1) & 1][0];
#pragma unroll
      for (int c = 0; c < 12; ++c)
        gload_lds16(kn + srcoff[c], kd + c * 2048 + tid * 16);
    }

    // ---- QK^T (split precision): 3 independent chains over 12 k-fragments ----
    const char* kc = &skv[t & 1][0];
    f32x4 shh = f32x4{0.f, 0.f, 0.f, 0.f}, shl = shh, slh = shh;
    __builtin_amdgcn_s_setprio(1);
#pragma unroll
    for (int kf = 0; kf < 12; ++kf) {
      bf16x8 ql = *(const bf16x8*)(qlp + kf * 32);
      const int ca = (kf * 64 + lg * 16) ^ swz;
      bf16x8 ah = *(const bf16x8*)(kc + ln15 * 768 + ca);
      bf16x8 al = *(const bf16x8*)(kc + 12288 + ln15 * 768 + ca);
      shh = __builtin_amdgcn_mfma_f32_16x16x32_bf16(ah, qh[kf], shh, 0, 0, 0);
      shl = __builtin_amdgcn_mfma_f32_16x16x32_bf16(ah, ql, shl, 0, 0, 0);
      slh = __builtin_amdgcn_mfma_f32_16x16x32_bf16(al, qh[kf], slh, 0, 0, 0);
    }
    __builtin_amdgcn_s_setprio(0);
    f32x4 s;
#pragma unroll
    for (int r = 0; r < 4; ++r) s[r] = shh[r] + shl[r] + slh[r];

    // ---- softmax (lane owns q=ln15; m = lg*4 + r) ----
    float tmax = fmaxf(fmaxf(s[0], s[1]), fmaxf(s[2], s[3]));
    tmax = fmaxf(tmax, __shfl_xor(tmax, 16));
    tmax = fmaxf(tmax, __shfl_xor(tmax, 32));
    if (__any(tmax - m1 > 8.f)) {                  // defer-max
      float mn = fmaxf(m1, tmax);
      float al_ = __expf(m1 - mn);
      float alr[4];
#pragma unroll
      for (int r = 0; r < 4; ++r) alr[r] = __shfl(al_, lg * 4 + r);
#pragma unroll
      for (int ob = 0; ob < 24; ++ob)
#pragma unroll
        for (int r = 0; r < 4; ++r) o[ob][r] *= alr[r];
      l1 *= al_;
      m1 = mn;
    }
    float rs = 0.0f;
#pragma unroll
    for (int r = 0; r < 4; ++r) {
      float p = __expf(s[r] - m1);
      rs += p;
      p8[r] = (short)f2bf(p);
    }
    rs += __shfl_xor(rs, 16);
    rs += __shfl_xor(rs, 32);
    l1 += rs;

    // ---- PV: O[q][d] += P * V, V-frags as coalesced b64 global loads ----
    // p8 k-slots 4..7 are zero -> v8 high half is don't-care (kept zero).
    const char* vf = vfb + (size_t)t * 12288;
    __builtin_amdgcn_s_setprio(1);
#pragma unroll
    for (int ch = 0; ch < 4; ++ch) {
      bf16x4 vv[6];
#pragma unroll
      for (int j = 0; j < 6; ++j) vv[j] = *(const bf16x4*)(vf + (ch * 6 + j) * 512);
#pragma unroll
      for (int j = 0; j < 6; ++j) {
        bf16x8 v8 = bf16x8{vv[j][0], vv[j][1], vv[j][2], vv[j][3], 0, 0, 0, 0};
        o[ch * 6 + j] = __builtin_amdgcn_mfma_f32_16x16x32_bf16(p8, v8, o[ch * 6 + j], 0, 0, 0);
      }
    }
    __builtin_amdgcn_s_setprio(0);

    __syncthreads();   // K(t+1) complete; all waves done reading skv[t&1]
  }

  // epilogue: O /= l, store bf16
  float lr[4];
#pragma unroll
  for (int r = 0; r < 4; ++r) lr[r] = __shfl(l1, lg * 4 + r);
  short* ob_ = aout + ((size_t)b * NTOK + q0 + wave * 16) * DD;
#pragma unroll
  for (int db = 0; db < 24; ++db) {
#pragma unroll
    for (int r = 0; r < 4; ++r) {
      float v = o[db][r] / lr[r];
      ob_[(size_t)(lg * 4 + r) * DD + db * 16 + ln15] = (short)f2bf(v);
    }
  }
}

// ---------------- K3: MLP + residual + LN stats (32-row tiles, all-resident) ----
__global__ __launch_bounds__(128, 3)
void k_mlp(const short* __restrict__ aout, const short* __restrict__ w1t,
           const short* __restrict__ w2t, const float* __restrict__ b1,
           const float* __restrict__ b2, const short* __restrict__ xhi,
           const short* __restrict__ xlo, float* __restrict__ out,
           float* __restrict__ stats) {
  __shared__ __attribute__((aligned(16))) short hid[2 * 16 * 392];
  __shared__ float redS[2], redQ[2];
  const int tid = threadIdx.x, lane = tid & 63, wave = tid >> 6;
  const int ln15 = lane & 15, lg = lane >> 4;
  const int row0 = blockIdx.x * 32;
  const int bb = row0 / NTOK;

  bf16x8 a[12];
  {
    const short* ap = aout + (size_t)(row0 + wave * 16 + ln15) * DD + lg * 8;
#pragma unroll
    for (int kf = 0; kf < 12; ++kf) a[kf] = *(const bf16x8*)(ap + kf * 32);
  }
  short* hw = &hid[wave * 16 * 392];
#pragma unroll 1
  for (int cb = 0; cb < 24; ++cb) {
    f32x4 acc = f32x4{0.f, 0.f, 0.f, 0.f};
#pragma unroll
    for (int kf = 0; kf < 12; ++kf) {
      bf16x8 wf = *(const bf16x8*)(w1t + (size_t)(cb * 16 + ln15) * DD + kf * 32 + lg * 8);
      acc = __builtin_amdgcn_mfma_f32_16x16x32_bf16(a[kf], wf, acc, 0, 0, 0);
    }
    float bias = b1[cb * 16 + ln15];
#pragma unroll
    for (int r = 0; r < 4; ++r) {
      float v = fmaxf(acc[r] + bias, 0.0f);
      hw[(lg * 4 + r) * 392 + cb * 16 + ln15] = (short)f2bf(v);
    }
  }
  __syncthreads();
  bf16x8 h[12];
#pragma unroll
  for (int kf = 0; kf < 12; ++kf)
    h[kf] = *(const bf16x8*)(&hw[ln15 * 392 + kf * 32 + lg * 8]);
  float ts = 0.f, tq = 0.f;
#pragma unroll 1
  for (int cb = 0; cb < 24; ++cb) {
    f32x4 acc = f32x4{0.f, 0.f, 0.f, 0.f};
#pragma unroll
    for (int kf = 0; kf < 12; ++kf) {
      bf16x8 wf = *(const bf16x8*)(w2t + (size_t)(cb * 16 + ln15) * DD + kf * 32 + lg * 8);
      acc = __builtin_amdgcn_mfma_f32_16x16x32_bf16(h[kf], wf, acc, 0, 0, 0);
    }
    int col = cb * 16 + ln15;
    float bias = b2[col];
#pragma unroll
    for (int r = 0; r < 4; ++r) {
      size_t row = (size_t)row0 + wave * 16 + lg * 4 + r;
      size_t idx = row * DD + col;
      float xv = bf2f(xhi[idx]) + bf2f(xlo[idx]);
      float y = acc[r] + bias + xv;
      out[idx] = y;
      ts += y;
      tq += y * y;
    }
  }
#pragma unroll
  for (int off = 32; off; off >>= 1) {
    ts += __shfl_xor(ts, off);
    tq += __shfl_xor(tq, off);
  }
  if (lane == 0) { redS[wave] = ts; redQ[wave] = tq; }
  __syncthreads();
  if (tid == 0) {
    atomicAdd(&stats[bb], redS[0] + redS[1]);
    atomicAdd(&stats[16 + bb], redQ[0] + redQ[1]);
  }
}

// ---------------- K4: LayerNorm ----------------
__global__ void k_ln(float* __restrict__ out, const float* __restrict__ stats) {
  size_t i4 = ((size_t)blockIdx.x * 256 + threadIdx.x) * 4;
  int b = (int)(i4 / ((size_t)NTOK * DD));
  const float cnt = (float)(NTOK * DD);
  float mean = stats[b] / cnt;
  float var = stats[16 + b] / cnt - mean * mean;
  float inv = rsqrtf(var + EPS);
  f32x4 v = *(f32x4*)(out + i4);
#pragma unroll
  for (int j = 0; j < 4; ++j) v[j] = (v[j] - mean) * inv;
  *(f32x4*)(out + i4) = v;
}

// ---------------- launcher ----------------
extern "C" void kernel_launch(void* const* d_in, const int* in_sizes, int n_in,
                              void* d_out, int out_size, void* d_ws, size_t ws_size,
                              hipStream_t stream) {
  const float* x  = (const float*)d_in[0];
  const float* Wp = (const float*)d_in[1];
  const float* bp = (const float*)d_in[2];
  const float* W1 = (const float*)d_in[3];
  const float* b1 = (const float*)d_in[4];
  const float* W2 = (const float*)d_in[5];
  const float* b2 = (const float*)d_in[6];
  float* out = (float*)d_out;

  const size_t SZ = (size_t)SZB;   // 28,311,552 bytes
  char* ws = (char*)d_ws;
  short* xhi   = (short*)ws;
  short* xlo   = (short*)(ws + SZ);      // MUST stay at xhi+SZB (srcoff relies on it)
  short* vfrag = (short*)(ws + 2 * SZ);
  short* aout  = (short*)(ws + 3 * SZ);
  short* w1t   = (short*)(ws + 4 * SZ);
  short* w2t   = (short*)(ws + 4 * SZ + 294912);
  float* stats = (float*)(ws + 4 * SZ + 2 * 294912);
  const size_t need = 4 * SZ + 2 * 294912 + 128;
  if (ws_size < need) {
    fprintf(stderr, "kernel_launch: ws_size %zu < needed %zu\n", ws_size, need);
  }

  k_prep<<<13824, 256, 0, stream>>>(x, Wp, bp, xhi, xlo);
  k_vfrag<<<dim3(144, 16), 256, 0, stream>>>(xhi, vfrag);
  k_wprep<<<576, 256, 0, stream>>>(W1, W2, w1t, w2t);
  k_attn<<<1152, 128, 0, stream>>>(xhi, xlo, vfrag, aout);
  hipMemsetAsync(stats, 0, 32 * sizeof(float), stream);
  k_mlp<<<1152, 128, 0, stream>>>(aout, w1t, w2t, b1, b2, xhi, xlo, out, stats);
  k_ln<<<13824, 256, 0, stream>>>(out, stats);
}

// Round 6
// 932.343 us; speedup vs baseline: 3.2465x; 1.7665x over previous
//
#include <hip/hip_runtime.h>
#include <cstdio>
#include <cstdint>

#define BB 16
#define HH 48
#define WW 48
#define DD 384
#define NTOK 2304            // HH*WW
#define EPS 1e-5f
#define SZB 28311552u        // BB*NTOK*DD*2 bytes (one bf16 tensor); xlo = xhi + SZB

typedef __attribute__((ext_vector_type(4))) float f32x4;
typedef __attribute__((ext_vector_type(8))) short bf16x8;
typedef __attribute__((ext_vector_type(4))) short bf16x4;

__device__ __forceinline__ unsigned short f2bf(float f) {
  uint32_t u = __float_as_uint(f);
  uint32_t r = (u + 0x7FFFu + ((u >> 16) & 1u)) >> 16;
  return (unsigned short)r;
}
__device__ __forceinline__ float bf2f(short s) {
  return __uint_as_float(((uint32_t)(unsigned short)s) << 16);
}

typedef __attribute__((address_space(3))) uint32_t lds_u32;
typedef __attribute__((address_space(1))) const uint32_t glob_u32;
__device__ __forceinline__ void gload_lds16(const void* g, void* l) {
  __builtin_amdgcn_global_load_lds((glob_u32*)g, (lds_u32*)l, 16, 0, 0);
}

// ---------------- K1: x + posenc -> hi/lo bf16 ----------------
__global__ void k_prep(const float* __restrict__ x, const float* __restrict__ Wp,
                       const float* __restrict__ bp, short* __restrict__ xhi,
                       short* __restrict__ xlo) {
  size_t e = ((size_t)blockIdx.x * 256 + threadIdx.x) * 4;
  int d = (int)(e % DD);
  int n = (int)((e / DD) % NTOK);
  float fh = (float)(n / WW), fw = (float)(n % WW);
  f32x4 v = *(const f32x4*)(x + e);
  bf16x4 hv, lv;
#pragma unroll
  for (int j = 0; j < 4; ++j) {
    float pe = fh * Wp[d + j] + fw * Wp[DD + d + j] + bp[d + j];
    float val = v[j] + pe;
    unsigned short hb = f2bf(val);
    hv[j] = (short)hb;
    lv[j] = (short)f2bf(val - bf2f((short)hb));
  }
  *(bf16x4*)(xhi + e) = hv;
  *(bf16x4*)(xlo + e) = lv;
}

// ---------------- KV: fragment-ordered V tensor for k=32 PV ----------------
// vfrag[b][pt=0..71][db=0..23][lane=0..63][j=0..7]
//   = xhi[b][pt*32 + tok][db*16 + (lane&15)],
//   tok = (j<4) ? (lane>>4)*4+j : 16 + (lane>>4)*4 + (j-4)
// This matches the MFMA 16x16x32 B-operand slot map for lane-local P slots.
__global__ void k_vfrag(const short* __restrict__ xhi, short* __restrict__ vfrag) {
  __shared__ __attribute__((aligned(16))) short tile[32 * 392];
  const int b = blockIdx.y, pt = blockIdx.x, tid = threadIdx.x;
  const short* src = xhi + ((size_t)b * NTOK + pt * 32) * DD;
#pragma unroll
  for (int c = 0; c < 6; ++c) {
    int u = c * 256 + tid;          // 0..1535; row = u/48, col8 = u%48
    int r = u / 48, c8 = u % 48;
    *(bf16x8*)(&tile[r * 392 + c8 * 8]) = *(const bf16x8*)(src + (size_t)r * DD + c8 * 8);
  }
  __syncthreads();
  char* dst = (char*)vfrag + ((size_t)b * 72 + pt) * 24576;
#pragma unroll
  for (int c = 0; c < 6; ++c) {
    int u = c * 256 + tid;          // db = u>>6, l = u&63
    int db = u >> 6, l = u & 63, l15 = l & 15, lgv = l >> 4;
    bf16x8 vv;
#pragma unroll
    for (int j = 0; j < 8; ++j) {
      int tok = (j < 4) ? (lgv * 4 + j) : (16 + lgv * 4 + (j - 4));
      vv[j] = tile[tok * 392 + db * 16 + l15];
    }
    *(bf16x8*)(dst + (size_t)u * 16) = vv;
  }
}

// ---------------- KW: W1^T, W2^T bf16 ----------------
__global__ void k_wprep(const float* __restrict__ W1, const float* __restrict__ W2,
                        short* __restrict__ w1t, short* __restrict__ w2t) {
  int idx = blockIdx.x * 256 + threadIdx.x;
  int r = idx / DD, c = idx % DD;
  w1t[c * DD + r] = (short)f2bf(W1[idx]);
  w2t[c * DD + r] = (short)f2bf(W2[idx]);
}

// ---------------- K2: flash attention ----------------
// QT=96 (6 waves), KVB=32 pairs. One batch per XCD per launch (b = b0 + bid&7).
// K hi+lo in LDS (two 16-row half-buffers, XOR-swizzled), P lane-local,
// V from fragment-ordered global tensor. LDS padded to 90KB -> 1 block/CU.
#define NPAIR 72

__global__ __launch_bounds__(384, 2)
void k_attn(const short* __restrict__ xhi, const short* __restrict__ xlo,
            const short* __restrict__ vfrag, short* __restrict__ aout, int b0) {
  __shared__ __attribute__((aligned(16))) char lds_all[90112];
  char* kb0 = lds_all;
  char* kb1 = lds_all + 24576;
  const int tid = threadIdx.x;
  const int lane = tid & 63, wave = tid >> 6;      // wave 0..5
  const int ln15 = lane & 15, lg = lane >> 4;
  const int b = b0 + (blockIdx.x & 7);             // one batch per XCD
  const int qt = blockIdx.x >> 3;                  // 0..23
  const int q0 = qt * 96;
  const int swz = (ln15 & 7) << 4;

  // DMA source offsets (dest linear: c*6144 + tid*16); source pre-swizzled.
  uint32_t srcoff[4];
#pragma unroll
  for (int c = 0; c < 4; ++c) {
    int g = c * 6144 + tid * 16;                   // dest byte in 24576B half-tile
    int region = (g >= 12288) ? 1 : 0;             // 0 = hi, 1 = lo
    int rem = g - region * 12288;
    int row = rem / 768;
    int col = rem - row * 768;
    srcoff[c] = (uint32_t)(row * 768 + (col ^ ((row & 7) << 4))) + (region ? SZB : 0u);
  }
  const char* kbp = (const char*)xhi + (size_t)b * NTOK * 768;
  const char* vfb = (const char*)vfrag + (size_t)b * 1769472 + lane * 16;

  // Q hi fragments resident; Q lo streamed (L1/L2-hot)
  bf16x8 qh[12];
  {
    const short* qp = xhi + ((size_t)b * NTOK + q0 + wave * 16 + ln15) * DD + lg * 8;
#pragma unroll
    for (int kf = 0; kf < 12; ++kf) qh[kf] = *(const bf16x8*)(qp + kf * 32);
  }
  const short* qlp = xlo + ((size_t)b * NTOK + q0 + wave * 16 + ln15) * DD + lg * 8;

  f32x4 o[24];
#pragma unroll
  for (int i = 0; i < 24; ++i) o[i] = f32x4{0.f, 0.f, 0.f, 0.f};
  float m1 = -INFINITY, l1 = 0.0f;

  // prologue: stage kb0(pair 0)
#pragma unroll
  for (int c = 0; c < 4; ++c)
    gload_lds16(kbp + srcoff[c], kb0 + c * 6144 + tid * 16);
  __syncthreads();

#pragma unroll 1
  for (int p = 0; p < NPAIR; ++p) {
    // issue kb1(p) — drains at barB, covered by even-QK
#pragma unroll
    for (int c = 0; c < 4; ++c)
      gload_lds16(kbp + 12288 + srcoff[c], kb1 + c * 6144 + tid * 16);

    // ---- even QK (kb0: keys p*32+0..15), 3 independent chains ----
    f32x4 shh = f32x4{0.f, 0.f, 0.f, 0.f}, shl = shh, slh = shh;
    __builtin_amdgcn_s_setprio(1);
#pragma unroll
    for (int kf = 0; kf < 12; ++kf) {
      bf16x8 ql = *(const bf16x8*)(qlp + kf * 32);
      const int ca = (kf * 64 + lg * 16) ^ swz;
      bf16x8 ah = *(const bf16x8*)(kb0 + ln15 * 768 + ca);
      bf16x8 al = *(const bf16x8*)(kb0 + 12288 + ln15 * 768 + ca);
      shh = __builtin_amdgcn_mfma_f32_16x16x32_bf16(ah, qh[kf], shh, 0, 0, 0);
      shl = __builtin_amdgcn_mfma_f32_16x16x32_bf16(ah, ql, shl, 0, 0, 0);
      slh = __builtin_amdgcn_mfma_f32_16x16x32_bf16(al, qh[kf], slh, 0, 0, 0);
    }
    __builtin_amdgcn_s_setprio(0);
    f32x4 sE;
#pragma unroll
    for (int r = 0; r < 4; ++r) sE[r] = shh[r] + shl[r] + slh[r];

    __syncthreads();   // barB: kb1(p) ready; kb0 free to overwrite

    // issue kb0(p+1) — drains at barA(next), covered by odd-QK+softmax+PV
    if (p + 1 < NPAIR) {
#pragma unroll
      for (int c = 0; c < 4; ++c)
        gload_lds16(kbp + 24576 + srcoff[c], kb0 + c * 6144 + tid * 16);
    }

    // ---- odd QK (kb1: keys p*32+16..31) ----
    shh = f32x4{0.f, 0.f, 0.f, 0.f}; shl = shh; slh = shh;
    __builtin_amdgcn_s_setprio(1);
#pragma unroll
    for (int kf = 0; kf < 12; ++kf) {
      bf16x8 ql = *(const bf16x8*)(qlp + kf * 32);
      const int ca = (kf * 64 + lg * 16) ^ swz;
      bf16x8 ah = *(const bf16x8*)(kb1 + ln15 * 768 + ca);
      bf16x8 al = *(const bf16x8*)(kb1 + 12288 + ln15 * 768 + ca);
      shh = __builtin_amdgcn_mfma_f32_16x16x32_bf16(ah, qh[kf], shh, 0, 0, 0);
      shl = __builtin_amdgcn_mfma_f32_16x16x32_bf16(ah, ql, shl, 0, 0, 0);
      slh = __builtin_amdgcn_mfma_f32_16x16x32_bf16(al, qh[kf], slh, 0, 0, 0);
    }
    __builtin_amdgcn_s_setprio(0);
    f32x4 sO;
#pragma unroll
    for (int r = 0; r < 4; ++r) sO[r] = shh[r] + shl[r] + slh[r];

    // ---- softmax over 32 keys (lane owns q=ln15; keys lg*4+r / 16+lg*4+r) ----
    float tmax = -INFINITY;
#pragma unroll
    for (int r = 0; r < 4; ++r) tmax = fmaxf(tmax, fmaxf(sE[r], sO[r]));
    tmax = fmaxf(tmax, __shfl_xor(tmax, 16));
    tmax = fmaxf(tmax, __shfl_xor(tmax, 32));
    if (__any(tmax - m1 > 8.f)) {                  // defer-max
      float mn = fmaxf(m1, tmax);
      float al_ = __expf(m1 - mn);
      float alr[4];
#pragma unroll
      for (int r = 0; r < 4; ++r) alr[r] = __shfl(al_, lg * 4 + r);
#pragma unroll
      for (int ob = 0; ob < 24; ++ob)
#pragma unroll
        for (int r = 0; r < 4; ++r) o[ob][r] *= alr[r];
      l1 *= al_;
      m1 = mn;
    }
    float rs = 0.0f;
    bf16x8 p8;
#pragma unroll
    for (int r = 0; r < 4; ++r) {
      float pe = __expf(sE[r] - m1);
      float po = __expf(sO[r] - m1);
      rs += pe + po;
      p8[r] = (short)f2bf(pe);
      p8[r + 4] = (short)f2bf(po);
    }
    rs += __shfl_xor(rs, 16);
    rs += __shfl_xor(rs, 32);
    l1 += rs;

    // ---- PV: one k=32 MFMA per 16-d block, V prefetched 6-deep ----
    const char* vf = vfb + (size_t)p * 24576;
    bf16x8 vA[6], vB[6];
#pragma unroll
    for (int j = 0; j < 6; ++j) vA[j] = *(const bf16x8*)(vf + j * 1024);
#pragma unroll
    for (int g = 0; g < 4; ++g) {
      const bf16x8* cur = (g & 1) ? vB : vA;
      bf16x8* nxt = (g & 1) ? vA : vB;
      if (g < 3) {
#pragma unroll
        for (int j = 0; j < 6; ++j) nxt[j] = *(const bf16x8*)(vf + (g + 1) * 6144 + j * 1024);
      }
      __builtin_amdgcn_s_setprio(1);
#pragma unroll
      for (int j = 0; j < 6; ++j)
        o[g * 6 + j] = __builtin_amdgcn_mfma_f32_16x16x32_bf16(p8, cur[j], o[g * 6 + j], 0, 0, 0);
      __builtin_amdgcn_s_setprio(0);
    }

    __syncthreads();   // barA: kb0(p+1) ready; kb1 free to overwrite
    kbp += 24576;      // advance 32 tokens
  }

  // epilogue: O /= l, store bf16
  float lr[4];
#pragma unroll
  for (int r = 0; r < 4; ++r) lr[r] = __shfl(l1, lg * 4 + r);
  short* ob_ = aout + ((size_t)b * NTOK + q0 + wave * 16) * DD;
#pragma unroll
  for (int db = 0; db < 24; ++db) {
#pragma unroll
    for (int r = 0; r < 4; ++r) {
      float v = o[db][r] / lr[r];
      ob_[(size_t)(lg * 4 + r) * DD + db * 16 + ln15] = (short)f2bf(v);
    }
  }
}

// ---------------- K3: MLP + residual + LN stats ----------------
__global__ __launch_bounds__(128, 3)
void k_mlp(const short* __restrict__ aout, const short* __restrict__ w1t,
           const short* __restrict__ w2t, const float* __restrict__ b1,
           const float* __restrict__ b2, const short* __restrict__ xhi,
           const short* __restrict__ xlo, float* __restrict__ out,
           float* __restrict__ stats) {
  __shared__ __attribute__((aligned(16))) short hid[2 * 16 * 392];
  __shared__ float redS[2], redQ[2];
  const int tid = threadIdx.x, lane = tid & 63, wave = tid >> 6;
  const int ln15 = lane & 15, lg = lane >> 4;
  const int row0 = blockIdx.x * 32;
  const int bb = row0 / NTOK;

  bf16x8 a[12];
  {
    const short* ap = aout + (size_t)(row0 + wave * 16 + ln15) * DD + lg * 8;
#pragma unroll
    for (int kf = 0; kf < 12; ++kf) a[kf] = *(const bf16x8*)(ap + kf * 32);
  }
  short* hw = &hid[wave * 16 * 392];
#pragma unroll 1
  for (int cb = 0; cb < 24; ++cb) {
    f32x4 acc = f32x4{0.f, 0.f, 0.f, 0.f};
#pragma unroll
    for (int kf = 0; kf < 12; ++kf) {
      bf16x8 wf = *(const bf16x8*)(w1t + (size_t)(cb * 16 + ln15) * DD + kf * 32 + lg * 8);
      acc = __builtin_amdgcn_mfma_f32_16x16x32_bf16(a[kf], wf, acc, 0, 0, 0);
    }
    float bias = b1[cb * 16 + ln15];
#pragma unroll
    for (int r = 0; r < 4; ++r) {
      float v = fmaxf(acc[r] + bias, 0.0f);
      hw[(lg * 4 + r) * 392 + cb * 16 + ln15] = (short)f2bf(v);
    }
  }
  __syncthreads();
  bf16x8 h[12];
#pragma unroll
  for (int kf = 0; kf < 12; ++kf)
    h[kf] = *(const bf16x8*)(&hw[ln15 * 392 + kf * 32 + lg * 8]);
  float ts = 0.f, tq = 0.f;
#pragma unroll 1
  for (int cb = 0; cb < 24; ++cb) {
    f32x4 acc = f32x4{0.f, 0.f, 0.f, 0.f};
#pragma unroll
    for (int kf = 0; kf < 12; ++kf) {
      bf16x8 wf = *(const bf16x8*)(w2t + (size_t)(cb * 16 + ln15) * DD + kf * 32 + lg * 8);
      acc = __builtin_amdgcn_mfma_f32_16x16x32_bf16(h[kf], wf, acc, 0, 0, 0);
    }
    int col = cb * 16 + ln15;
    float bias = b2[col];
#pragma unroll
    for (int r = 0; r < 4; ++r) {
      size_t row = (size_t)row0 + wave * 16 + lg * 4 + r;
      size_t idx = row * DD + col;
      float xv = bf2f(xhi[idx]) + bf2f(xlo[idx]);
      float y = acc[r] + bias + xv;
      out[idx] = y;
      ts += y;
      tq += y * y;
    }
  }
#pragma unroll
  for (int off = 32; off; off >>= 1) {
    ts += __shfl_xor(ts, off);
    tq += __shfl_xor(tq, off);
  }
  if (lane == 0) { redS[wave] = ts; redQ[wave] = tq; }
  __syncthreads();
  if (tid == 0) {
    atomicAdd(&stats[bb], redS[0] + redS[1]);
    atomicAdd(&stats[16 + bb], redQ[0] + redQ[1]);
  }
}

// ---------------- K4: LayerNorm ----------------
__global__ void k_ln(float* __restrict__ out, const float* __restrict__ stats) {
  size_t i4 = ((size_t)blockIdx.x * 256 + threadIdx.x) * 4;
  int b = (int)(i4 / ((size_t)NTOK * DD));
  const float cnt = (float)(NTOK * DD);
  float mean = stats[b] / cnt;
  float var = stats[16 + b] / cnt - mean * mean;
  float inv = rsqrtf(var + EPS);
  f32x4 v = *(f32x4*)(out + i4);
#pragma unroll
  for (int j = 0; j < 4; ++j) v[j] = (v[j] - mean) * inv;
  *(f32x4*)(out + i4) = v;
}

// ---------------- launcher ----------------
extern "C" void kernel_launch(void* const* d_in, const int* in_sizes, int n_in,
                              void* d_out, int out_size, void* d_ws, size_t ws_size,
                              hipStream_t stream) {
  const float* x  = (const float*)d_in[0];
  const float* Wp = (const float*)d_in[1];
  const float* bp = (const float*)d_in[2];
  const float* W1 = (const float*)d_in[3];
  const float* b1 = (const float*)d_in[4];
  const float* W2 = (const float*)d_in[5];
  const float* b2 = (const float*)d_in[6];
  float* out = (float*)d_out;

  const size_t SZ = (size_t)SZB;   // 28,311,552 bytes
  char* ws = (char*)d_ws;
  short* xhi   = (short*)ws;
  short* xlo   = (short*)(ws + SZ);      // MUST stay at xhi+SZB (srcoff relies on it)
  short* vfrag = (short*)(ws + 2 * SZ);
  short* aout  = (short*)(ws + 3 * SZ);
  short* w1t   = (short*)(ws + 4 * SZ);
  short* w2t   = (short*)(ws + 4 * SZ + 294912);
  float* stats = (float*)(ws + 4 * SZ + 2 * 294912);
  const size_t need = 4 * SZ + 2 * 294912 + 128;
  if (ws_size < need) {
    fprintf(stderr, "kernel_launch: ws_size %zu < needed %zu\n", ws_size, need);
  }

  k_prep<<<13824, 256, 0, stream>>>(x, Wp, bp, xhi, xlo);
  k_vfrag<<<dim3(72, 16), 256, 0, stream>>>(xhi, vfrag);
  k_wprep<<<576, 256, 0, stream>>>(W1, W2, w1t, w2t);
  k_attn<<<192, 384, 0, stream>>>(xhi, xlo, vfrag, aout, 0);   // batches 0-7, 1/XCD
  k_attn<<<192, 384, 0, stream>>>(xhi, xlo, vfrag, aout, 8);   // batches 8-15
  hipMemsetAsync(stats, 0, 32 * sizeof(float), stream);
  k_mlp<<<1152, 128, 0, stream>>>(aout, w1t, w2t, b1, b2, xhi, xlo, out, stats);
  k_ln<<<13824, 256, 0, stream>>>(out, stats);
}